// Round 15
// baseline (55.696 us; speedup 1.0000x reference)
//
#include <hip/hip_runtime.h>

// Fused attention block: B=4, S=2048, F=512, D=64
//  q = x@Wq + bq ; k = x@Wk + bk ; v = x@Wv + bv      (B,S,D)
//  logits = q@k^T / 8 + (1-mask)*-1e9 ; attn = softmax ; out = attn@v
//
// R15 = R14 + cross-iteration K+mask software prefetch in attn:
//  - Each iteration's K fragments are consumed at its TOP by QK^T; the asm
//    fences prevent the compiler hoisting next-iter K loads across -> ~400cy
//    L2 latency exposed per iter. Fix: prefetch next-iter K + mask right
//    after QK^T, landing under softmax+exchange (~1000cy of cover).
//  - SAFE variant of R9's idea: NO __launch_bounds__ VGPR cap (R9/R11's
//    spills are attributed to the (512,4) 128-VGPR cap), and the 4 k-iters
//    are expanded via an explicit macro over two NAMED buffer sets (kfP/kfQ
//    rotated textually) -> every register-array index is a compile-time
//    constant regardless of unroll decisions (rule #20).
//  Peak live VGPR ~175 < 256 spill point; occupancy unchanged.
//
// MFMA v_mfma_f32_16x16x32_bf16 fragment layouts (guide §3, m89/m91):
//   A: lane holds A[row = lane&15][k = (lane>>4)*8 + e], e=0..7
//   B: lane holds B[k = (lane>>4)*8 + e][col = lane&15]
//   C/D: lane holds D[row = (lane>>4)*4 + r][col = lane&15], r=0..3

typedef __attribute__((ext_vector_type(8))) short bhalf8;
typedef __attribute__((ext_vector_type(4))) float fx4;

#define MFMA(a, b, c) __builtin_amdgcn_mfma_f32_16x16x32_bf16((a), (b), (c), 0, 0, 0)

__device__ __forceinline__ short f2bf(float f) {
    union { float f; unsigned u; } v; v.f = f;
    unsigned r = (v.u + 0x7FFFu + ((v.u >> 16) & 1u)) >> 16;  // RNE
    return (short)r;
}

__device__ __forceinline__ unsigned cvt_pk_bf16(float lo, float hi) {
    unsigned r;
    asm("v_cvt_pk_bf16_f32 %0, %1, %2" : "=v"(r) : "v"(lo), "v"(hi));
    return r;
}

// Build B-fragment B[k0+e][col] (e=0..7) from row-major f32 W[512][64].
__device__ __forceinline__ bhalf8 wfrag(const float* __restrict__ W, int k0, int col) {
    union { unsigned u[4]; bhalf8 h; } r;
#pragma unroll
    for (int e2 = 0; e2 < 4; ++e2)
        r.u[e2] = cvt_pk_bf16(W[(k0 + 2 * e2) * 64 + col],
                              W[(k0 + 2 * e2 + 1) * 64 + col]);
    return r.h;
}

// ---- Kernel 1: QKV projection, conversion fused (R8 verbatim). ----
__global__ __launch_bounds__(256) void proj_kernel(
    const float* __restrict__ x,
    const float* __restrict__ Wq, const float* __restrict__ bq,
    const float* __restrict__ Wk, const float* __restrict__ bk,
    const float* __restrict__ Wv, const float* __restrict__ bv,
    short* __restrict__ Qb, short* __restrict__ Kb, short* __restrict__ Vt)
{
    const int tid  = threadIdx.x;
    const int lane = tid & 63;
    const int wid  = tid >> 6;              // col-quarter 0..3
    const int g = lane >> 4, c = lane & 15;
    const int rowbase = blockIdx.x * 16;

    __shared__ __align__(16) short xs[16][520];

#pragma unroll
    for (int i = 0; i < 4; ++i) {
        const int id  = tid + i * 256;
        const int row = id >> 6;
        const int col8 = (id & 63) * 8;
        const float* xp = x + (size_t)(rowbase + row) * 512 + col8;
        const float4 f0 = *(const float4*)(xp);
        const float4 f1 = *(const float4*)(xp + 4);
        union { unsigned u[4]; uint4 v; } wv;
        wv.u[0] = cvt_pk_bf16(f0.x, f0.y);
        wv.u[1] = cvt_pk_bf16(f0.z, f0.w);
        wv.u[2] = cvt_pk_bf16(f1.x, f1.y);
        wv.u[3] = cvt_pk_bf16(f1.z, f1.w);
        *(uint4*)&xs[row][col8] = wv.v;
    }
    __syncthreads();

    const int col = wid * 16 + c;
    fx4 aq = (fx4){0.f, 0.f, 0.f, 0.f};
    fx4 ak = (fx4){0.f, 0.f, 0.f, 0.f};
    fx4 av = (fx4){0.f, 0.f, 0.f, 0.f};

#pragma unroll 4
    for (int ks = 0; ks < 16; ++ks) {
        const int k0 = ks * 32 + g * 8;
        const bhalf8 a = *(const bhalf8*)&xs[c][k0];
        aq = MFMA(a, wfrag(Wq, k0, col), aq);
        ak = MFMA(a, wfrag(Wk, k0, col), ak);
        av = MFMA(a, wfrag(Wv, k0, col), av);
    }

    const float bq_ = bq[col], bk_ = bk[col], bv_ = bv[col];
#pragma unroll
    for (int r = 0; r < 4; ++r) {
        const int row = rowbase + g * 4 + r;
        Qb[row * 64 + col] = f2bf(aq[r] + bq_);
        Kb[row * 64 + col] = f2bf(ak[r] + bk_);
        const int s = row & 2047, b_ = row >> 11;
        const int sp = (s & ~63) | (((s >> 4) & 3) + (s & 15) * 4);
        Vt[((size_t)b_ * 64 + col) * 2048 + sp] = f2bf(av[r] + bv_);
    }
}

// One attention k-iteration for both q-tiles. KF/MK = current K-frag + mask
// buffers (consumed); KFN/MKN = next-iter buffers (filled if PF). All array
// indices inside are compile-time constants (unrolled t/r loops on named
// arrays) -> registers, never scratch.
#define ATTN_ITER(KB, KF, MK, KFN, MKN, PF, KBN)                              \
  {                                                                           \
    const int kb = (KB);                                                      \
    fx4 sA[4], sB[4];                                                         \
    __builtin_amdgcn_s_setprio(1);                                            \
    _Pragma("unroll")                                                         \
    for (int t = 0; t < 4; ++t) {                                             \
        fx4 zA = (fx4){0.f, 0.f, 0.f, 0.f};                                   \
        zA = MFMA(qfA0, KF[t][0], zA);                                        \
        sA[t] = MFMA(qfA1, KF[t][1], zA);                                     \
        fx4 zB = (fx4){0.f, 0.f, 0.f, 0.f};                                   \
        zB = MFMA(qfB0, KF[t][0], zB);                                        \
        sB[t] = MFMA(qfB1, KF[t][1], zB);                                     \
    }                                                                         \
    __builtin_amdgcn_s_setprio(0);                                            \
    if (PF) {  /* prefetch next-iter K + mask; lands under softmax */         \
        _Pragma("unroll")                                                     \
        for (int t = 0; t < 4; ++t) {                                         \
            const short* kp = Kp + (size_t)((KBN) + t * 16 + c) * 64 + g * 8; \
            KFN[t][0] = *(const bhalf8*)(kp);                                 \
            KFN[t][1] = *(const bhalf8*)(kp + 32);                            \
            MKN[t] = mp[(KBN) + t * 16 + c];                                  \
        }                                                                     \
    }                                                                         \
    bhalf8 vf[4][2];                                                          \
    _Pragma("unroll")                                                         \
    for (int dt = 0; dt < 4; ++dt) {                                          \
        const short* vp = Vp + (size_t)(dt * 16 + c) * 2048 + kb + g * 8;     \
        vf[dt][0] = *(const bhalf8*)(vp);                                     \
        vf[dt][1] = *(const bhalf8*)(vp + 32);                                \
    }                                                                         \
    float madd[4];                                                            \
    _Pragma("unroll")                                                         \
    for (int t = 0; t < 4; ++t) madd[t] = MK[t] ? 0.f : -1e9f;                \
    float pA[4][4], pB[4][4];                                                 \
    {                                                                         \
        float tm[4];                                                          \
        _Pragma("unroll")                                                     \
        for (int r = 0; r < 4; ++r) {                                         \
            tm[r] = -1e30f;                                                   \
            _Pragma("unroll")                                                 \
            for (int t = 0; t < 4; ++t) {                                     \
                pA[t][r] = sA[t][r] * 0.125f + madd[t];                       \
                tm[r] = fmaxf(tm[r], pA[t][r]);                               \
            }                                                                 \
        }                                                                     \
        _Pragma("unroll")                                                     \
        for (int r = 0; r < 4; ++r) {                                         \
            tm[r] = fmaxf(tm[r], __shfl_xor(tm[r], 1));                       \
            tm[r] = fmaxf(tm[r], __shfl_xor(tm[r], 2));                       \
            tm[r] = fmaxf(tm[r], __shfl_xor(tm[r], 4));                       \
            tm[r] = fmaxf(tm[r], __shfl_xor(tm[r], 8));                       \
        }                                                                     \
        _Pragma("unroll")                                                     \
        for (int r = 0; r < 4; ++r) {                                         \
            const float nm = fmaxf(mA[r], tm[r]);                             \
            const float fac = __expf(mA[r] - nm);                             \
            mA[r] = nm;                                                       \
            float rs = 0.f;                                                   \
            _Pragma("unroll")                                                 \
            for (int t = 0; t < 4; ++t) {                                     \
                pA[t][r] = __expf(pA[t][r] - nm);                             \
                rs += pA[t][r];                                               \
            }                                                                 \
            rs += __shfl_xor(rs, 1);                                          \
            rs += __shfl_xor(rs, 2);                                          \
            rs += __shfl_xor(rs, 4);                                          \
            rs += __shfl_xor(rs, 8);                                          \
            lA[r] = lA[r] * fac + rs;                                         \
            _Pragma("unroll")                                                 \
            for (int dt = 0; dt < 4; ++dt) oA[dt][r] *= fac;                  \
        }                                                                     \
    }                                                                         \
    {                                                                         \
        float tm[4];                                                          \
        _Pragma("unroll")                                                     \
        for (int r = 0; r < 4; ++r) {                                         \
            tm[r] = -1e30f;                                                   \
            _Pragma("unroll")                                                 \
            for (int t = 0; t < 4; ++t) {                                     \
                pB[t][r] = sB[t][r] * 0.125f + madd[t];                       \
                tm[r] = fmaxf(tm[r], pB[t][r]);                               \
            }                                                                 \
        }                                                                     \
        _Pragma("unroll")                                                     \
        for (int r = 0; r < 4; ++r) {                                         \
            tm[r] = fmaxf(tm[r], __shfl_xor(tm[r], 1));                       \
            tm[r] = fmaxf(tm[r], __shfl_xor(tm[r], 2));                       \
            tm[r] = fmaxf(tm[r], __shfl_xor(tm[r], 4));                       \
            tm[r] = fmaxf(tm[r], __shfl_xor(tm[r], 8));                       \
        }                                                                     \
        _Pragma("unroll")                                                     \
        for (int r = 0; r < 4; ++r) {                                         \
            const float nm = fmaxf(mB[r], tm[r]);                             \
            const float fac = __expf(mB[r] - nm);                             \
            mB[r] = nm;                                                       \
            float rs = 0.f;                                                   \
            _Pragma("unroll")                                                 \
            for (int t = 0; t < 4; ++t) {                                     \
                pB[t][r] = __expf(pB[t][r] - nm);                             \
                rs += pB[t][r];                                               \
            }                                                                 \
            rs += __shfl_xor(rs, 1);                                          \
            rs += __shfl_xor(rs, 2);                                          \
            rs += __shfl_xor(rs, 4);                                          \
            rs += __shfl_xor(rs, 8);                                          \
            lB[r] = lB[r] * fac + rs;                                         \
            _Pragma("unroll")                                                 \
            for (int dt = 0; dt < 4; ++dt) oB[dt][r] *= fac;                  \
        }                                                                     \
    }                                                                         \
    /* merged fenced P-exchange (fences load-bearing: R7 lesson) */           \
    asm volatile("" ::: "memory");                                            \
    _Pragma("unroll")                                                         \
    for (int r = 0; r < 4; ++r) {                                             \
        uint2 wA, wB;                                                         \
        wA.x = cvt_pk_bf16(pA[0][r], pA[1][r]);                               \
        wA.y = cvt_pk_bf16(pA[2][r], pA[3][r]);                               \
        *(uint2*)&Plds[wid][0][g * 4 + r][c * 4] = wA;                        \
        wB.x = cvt_pk_bf16(pB[0][r], pB[1][r]);                               \
        wB.y = cvt_pk_bf16(pB[2][r], pB[3][r]);                               \
        *(uint2*)&Plds[wid][1][g * 4 + r][c * 4] = wB;                        \
    }                                                                         \
    asm volatile("s_waitcnt lgkmcnt(0)" ::: "memory");                        \
    const bhalf8 paA0 = *(const bhalf8*)(&Plds[wid][0][c][g * 8]);            \
    const bhalf8 paA1 = *(const bhalf8*)(&Plds[wid][0][c][32 + g * 8]);       \
    const bhalf8 paB0 = *(const bhalf8*)(&Plds[wid][1][c][g * 8]);            \
    const bhalf8 paB1 = *(const bhalf8*)(&Plds[wid][1][c][32 + g * 8]);       \
    __builtin_amdgcn_s_setprio(1);                                            \
    _Pragma("unroll")                                                         \
    for (int dt = 0; dt < 4; ++dt) {                                          \
        oA[dt] = MFMA(paA0, vf[dt][0], oA[dt]);                               \
        oA[dt] = MFMA(paA1, vf[dt][1], oA[dt]);                               \
        oB[dt] = MFMA(paB0, vf[dt][0], oB[dt]);                               \
        oB[dt] = MFMA(paB1, vf[dt][1], oB[dt]);                               \
    }                                                                         \
    __builtin_amdgcn_s_setprio(0);                                            \
  }

// ---- Kernel 2: flash attention. 8 waves/block, 32 q-rows/block (2 tiles
// per wave sharing K/V fragments), K+mask prefetch via named double buffers,
// merged-fence P-exchange, setprio, LDS combine. grid 256 ----
__global__ __launch_bounds__(512) void attn_kernel(const short* __restrict__ Qb,
                                                   const short* __restrict__ Kb,
                                                   const short* __restrict__ Vt,
                                                   const int* __restrict__ mask,
                                                   float* __restrict__ out) {
    const int tid  = threadIdx.x;
    const int wid  = tid >> 6;
    const int lane = tid & 63;
    const int g = lane >> 4, c = lane & 15;
    const int b     = blockIdx.x >> 6;          // 64 blocks per batch
    const int qbase = (blockIdx.x & 63) << 5;   // 32 rows per block
    const short* Qp = Qb + (size_t)(b * 2048 + qbase) * 64;
    const short* Kp = Kb + (size_t)b * 2048 * 64;
    const short* Vp = Vt + (size_t)b * 64 * 2048;
    const int*   mp = mask + b * 2048;

    // Q fragments: tile A = rows 0..15, tile B = rows 16..31
    const bhalf8 qfA0 = *(const bhalf8*)(Qp + c * 64 + g * 8);
    const bhalf8 qfA1 = *(const bhalf8*)(Qp + c * 64 + 32 + g * 8);
    const bhalf8 qfB0 = *(const bhalf8*)(Qp + (16 + c) * 64 + g * 8);
    const bhalf8 qfB1 = *(const bhalf8*)(Qp + (16 + c) * 64 + 32 + g * 8);

    float mA[4], lA[4], mB[4], lB[4];
    fx4 oA[4], oB[4];
#pragma unroll
    for (int r = 0; r < 4; ++r) { mA[r] = -1e30f; lA[r] = 0.f; mB[r] = -1e30f; lB[r] = 0.f; }
#pragma unroll
    for (int dt = 0; dt < 4; ++dt) { oA[dt] = (fx4){0.f, 0.f, 0.f, 0.f}; oB[dt] = (fx4){0.f, 0.f, 0.f, 0.f}; }

    __shared__ float olds[8][32][65];                   // 66.6 KB
    __shared__ float mlds[8][32];
    __shared__ float llds[8][32];
    __shared__ __align__(16) short Plds[8][2][16][72];  // 64 payload + 8 pad

    const int kbase = wid * 256;
    const int kb0 = kbase, kb1 = kbase + 64, kb2 = kbase + 128, kb3 = kbase + 192;

    // Named K/mask double buffers (textual rotation -> constant indices).
    bhalf8 kfP[4][2], kfQ[4][2];
    int    mkP[4], mkQ[4];
#pragma unroll
    for (int t = 0; t < 4; ++t) {
        const short* kp = Kp + (size_t)(kb0 + t * 16 + c) * 64 + g * 8;
        kfP[t][0] = *(const bhalf8*)(kp);
        kfP[t][1] = *(const bhalf8*)(kp + 32);
        mkP[t] = mp[kb0 + t * 16 + c];
    }

    ATTN_ITER(kb0, kfP, mkP, kfQ, mkQ, 1, kb1)
    ATTN_ITER(kb1, kfQ, mkQ, kfP, mkP, 1, kb2)
    ATTN_ITER(kb2, kfP, mkP, kfQ, mkQ, 1, kb3)
    ATTN_ITER(kb3, kfQ, mkQ, kfP, mkP, 0, kb3)

    // ---- publish per-wave partial state (rows 0..15 = A, 16..31 = B) ----
    if (c == 0) {
#pragma unroll
        for (int r = 0; r < 4; ++r) {
            mlds[wid][g * 4 + r]      = mA[r];
            llds[wid][g * 4 + r]      = lA[r];
            mlds[wid][16 + g * 4 + r] = mB[r];
            llds[wid][16 + g * 4 + r] = lB[r];
        }
    }
#pragma unroll
    for (int dt = 0; dt < 4; ++dt)
#pragma unroll
        for (int r = 0; r < 4; ++r) {
            olds[wid][g * 4 + r][dt * 16 + c]      = oA[dt][r];
            olds[wid][16 + g * 4 + r][dt * 16 + c] = oB[dt][r];
        }
    __syncthreads();

    // ---- cross-wave combine (2048 outputs, 4 per thread) ----
    float* op = out + (size_t)(b * 2048 + qbase) * 64;
#pragma unroll
    for (int i = 0; i < 4; ++i) {
        const int idx = tid + i * 512;        // 0..2047 over (row,d)
        const int row = idx >> 6, d = idx & 63;
        float M = mlds[0][row];
#pragma unroll
        for (int w = 1; w < 8; ++w) M = fmaxf(M, mlds[w][row]);
        float num = 0.f, den = 0.f;
#pragma unroll
        for (int w = 0; w < 8; ++w) {
            const float wt = __expf(mlds[w][row] - M);
            num += wt * olds[w][row][d];
            den += wt * llds[w][row];
        }
        op[row * 64 + d] = num / den;
    }
}

extern "C" void kernel_launch(void* const* d_in, const int* in_sizes, int n_in,
                              void* d_out, int out_size, void* d_ws, size_t ws_size,
                              hipStream_t stream) {
    const float* x    = (const float*)d_in[0];
    const int*   mask = (const int*)d_in[1];
    const float* Wq   = (const float*)d_in[2];
    const float* bq   = (const float*)d_in[3];
    const float* Wk   = (const float*)d_in[4];
    const float* bk   = (const float*)d_in[5];
    const float* Wv   = (const float*)d_in[6];
    const float* bv   = (const float*)d_in[7];
    float* out = (float*)d_out;

    short* Qb = (short*)d_ws;                 // 4*2048*64
    short* Kb = Qb + 4 * 2048 * 64;           // 4*2048*64
    short* Vt = Kb + 4 * 2048 * 64;           // 4*2048*64 ([B][64][2048], key-permuted)

    proj_kernel<<<512, 256, 0, stream>>>(x, Wq, bq, Wk, bk, Wv, bv, Qb, Kb, Vt);
    attn_kernel<<<256, 512, 0, stream>>>(Qb, Kb, Vt, mask, out);
}

// Round 16
// 39.722 us; speedup vs baseline: 1.4021x; 1.4021x over previous
//
#include <hip/hip_runtime.h>

// Fused attention block: B=4, S=2048, F=512, D=64
//  q = x@Wq + bq ; k = x@Wk + bk ; v = x@Wv + bv      (B,S,D)
//  logits = q@k^T / 8 + (1-mask)*-1e9 ; attn = softmax ; out = attn@v
//
// R16 = R12 VERBATIM (best measured: 39.66us).
// Lever ledger from R13-R15:
//  - merged-fence P-exchange + s_setprio: NEUTRAL (R14: 40.0 vs 39.7).
//  - cross-iteration K prefetch: POISON, 3x confirmed (R9/R11/R15): hipcc
//    pins this kernel at 128 VGPR even without a launch_bounds cap; the
//    extra cross-fence live state spills to scratch (+40-200MB HBM traffic).
//  - 4 q-tiles/wave: blocked (olds would be 133KB LDS > 160 budget w/ rest).
//  - proj 32-row: regressed (+2us, R10). proj 16-row stands.
// Remaining time ~= 15us harness/graph fixed + ~17us attn (latency-chain ~2x
// its L2 floor) + ~6us proj. No clean mechanism left that stays out of the
// spill regime -- this family is at its plateau.
//
// MFMA v_mfma_f32_16x16x32_bf16 fragment layouts (guide §3, m89/m91):
//   A: lane holds A[row = lane&15][k = (lane>>4)*8 + e], e=0..7
//   B: lane holds B[k = (lane>>4)*8 + e][col = lane&15]
//   C/D: lane holds D[row = (lane>>4)*4 + r][col = lane&15], r=0..3

typedef __attribute__((ext_vector_type(8))) short bhalf8;
typedef __attribute__((ext_vector_type(4))) float fx4;

#define MFMA(a, b, c) __builtin_amdgcn_mfma_f32_16x16x32_bf16((a), (b), (c), 0, 0, 0)

__device__ __forceinline__ short f2bf(float f) {
    union { float f; unsigned u; } v; v.f = f;
    unsigned r = (v.u + 0x7FFFu + ((v.u >> 16) & 1u)) >> 16;  // RNE
    return (short)r;
}

__device__ __forceinline__ unsigned cvt_pk_bf16(float lo, float hi) {
    unsigned r;
    asm("v_cvt_pk_bf16_f32 %0, %1, %2" : "=v"(r) : "v"(lo), "v"(hi));
    return r;
}

// Build B-fragment B[k0+e][col] (e=0..7) from row-major f32 W[512][64].
__device__ __forceinline__ bhalf8 wfrag(const float* __restrict__ W, int k0, int col) {
    union { unsigned u[4]; bhalf8 h; } r;
#pragma unroll
    for (int e2 = 0; e2 < 4; ++e2)
        r.u[e2] = cvt_pk_bf16(W[(k0 + 2 * e2) * 64 + col],
                              W[(k0 + 2 * e2 + 1) * 64 + col]);
    return r.h;
}

// ---- Kernel 1: QKV projection, conversion fused (R8 verbatim). ----
__global__ __launch_bounds__(256) void proj_kernel(
    const float* __restrict__ x,
    const float* __restrict__ Wq, const float* __restrict__ bq,
    const float* __restrict__ Wk, const float* __restrict__ bk,
    const float* __restrict__ Wv, const float* __restrict__ bv,
    short* __restrict__ Qb, short* __restrict__ Kb, short* __restrict__ Vt)
{
    const int tid  = threadIdx.x;
    const int lane = tid & 63;
    const int wid  = tid >> 6;              // col-quarter 0..3
    const int g = lane >> 4, c = lane & 15;
    const int rowbase = blockIdx.x * 16;

    __shared__ __align__(16) short xs[16][520];

#pragma unroll
    for (int i = 0; i < 4; ++i) {
        const int id  = tid + i * 256;
        const int row = id >> 6;
        const int col8 = (id & 63) * 8;
        const float* xp = x + (size_t)(rowbase + row) * 512 + col8;
        const float4 f0 = *(const float4*)(xp);
        const float4 f1 = *(const float4*)(xp + 4);
        union { unsigned u[4]; uint4 v; } wv;
        wv.u[0] = cvt_pk_bf16(f0.x, f0.y);
        wv.u[1] = cvt_pk_bf16(f0.z, f0.w);
        wv.u[2] = cvt_pk_bf16(f1.x, f1.y);
        wv.u[3] = cvt_pk_bf16(f1.z, f1.w);
        *(uint4*)&xs[row][col8] = wv.v;
    }
    __syncthreads();

    const int col = wid * 16 + c;
    fx4 aq = (fx4){0.f, 0.f, 0.f, 0.f};
    fx4 ak = (fx4){0.f, 0.f, 0.f, 0.f};
    fx4 av = (fx4){0.f, 0.f, 0.f, 0.f};

#pragma unroll 4
    for (int ks = 0; ks < 16; ++ks) {
        const int k0 = ks * 32 + g * 8;
        const bhalf8 a = *(const bhalf8*)&xs[c][k0];
        aq = MFMA(a, wfrag(Wq, k0, col), aq);
        ak = MFMA(a, wfrag(Wk, k0, col), ak);
        av = MFMA(a, wfrag(Wv, k0, col), av);
    }

    const float bq_ = bq[col], bk_ = bk[col], bv_ = bv[col];
#pragma unroll
    for (int r = 0; r < 4; ++r) {
        const int row = rowbase + g * 4 + r;
        Qb[row * 64 + col] = f2bf(aq[r] + bq_);
        Kb[row * 64 + col] = f2bf(ak[r] + bk_);
        const int s = row & 2047, b_ = row >> 11;
        const int sp = (s & ~63) | (((s >> 4) & 3) + (s & 15) * 4);
        Vt[((size_t)b_ * 64 + col) * 2048 + sp] = f2bf(av[r] + bv_);
    }
}

// ---- Kernel 2: flash attention. 8 waves/block, 32 q-rows/block (2 tiles
// per wave sharing K/V fragments), per-wave 256-key slice, private online
// softmax per tile, LDS combine. grid B*(S/32)=256 ----
__global__ __launch_bounds__(512) void attn_kernel(const short* __restrict__ Qb,
                                                   const short* __restrict__ Kb,
                                                   const short* __restrict__ Vt,
                                                   const int* __restrict__ mask,
                                                   float* __restrict__ out) {
    const int tid  = threadIdx.x;
    const int wid  = tid >> 6;
    const int lane = tid & 63;
    const int g = lane >> 4, c = lane & 15;
    const int b     = blockIdx.x >> 6;          // 64 blocks per batch
    const int qbase = (blockIdx.x & 63) << 5;   // 32 rows per block
    const short* Qp = Qb + (size_t)(b * 2048 + qbase) * 64;
    const short* Kp = Kb + (size_t)b * 2048 * 64;
    const short* Vp = Vt + (size_t)b * 64 * 2048;
    const int*   mp = mask + b * 2048;

    // Q fragments: tile A = rows 0..15, tile B = rows 16..31
    const bhalf8 qfA0 = *(const bhalf8*)(Qp + c * 64 + g * 8);
    const bhalf8 qfA1 = *(const bhalf8*)(Qp + c * 64 + 32 + g * 8);
    const bhalf8 qfB0 = *(const bhalf8*)(Qp + (16 + c) * 64 + g * 8);
    const bhalf8 qfB1 = *(const bhalf8*)(Qp + (16 + c) * 64 + 32 + g * 8);

    float mA[4], lA[4], mB[4], lB[4];
    fx4 oA[4], oB[4];
#pragma unroll
    for (int r = 0; r < 4; ++r) { mA[r] = -1e30f; lA[r] = 0.f; mB[r] = -1e30f; lB[r] = 0.f; }
#pragma unroll
    for (int dt = 0; dt < 4; ++dt) { oA[dt] = (fx4){0.f, 0.f, 0.f, 0.f}; oB[dt] = (fx4){0.f, 0.f, 0.f, 0.f}; }

    __shared__ float olds[8][32][65];                 // 66.6 KB
    __shared__ float mlds[8][32];
    __shared__ float llds[8][32];
    __shared__ __align__(16) short Plds[8][16][72];   // reused A then B

    for (int kt = 0; kt < 4; ++kt) {
        const int kb = (wid * 4 + kt) * 64;

        // ---- QK^T for BOTH tiles, sharing the K fragments ----
        fx4 sA[4], sB[4];
#pragma unroll
        for (int t = 0; t < 4; ++t) {
            const short* kp = Kp + (size_t)(kb + t * 16 + c) * 64 + g * 8;
            const bhalf8 kf0 = *(const bhalf8*)(kp);
            const bhalf8 kf1 = *(const bhalf8*)(kp + 32);
            fx4 zA = (fx4){0.f, 0.f, 0.f, 0.f};
            zA = MFMA(qfA0, kf0, zA);
            sA[t] = MFMA(qfA1, kf1, zA);
            fx4 zB = (fx4){0.f, 0.f, 0.f, 0.f};
            zB = MFMA(qfB0, kf0, zB);
            sB[t] = MFMA(qfB1, kf1, zB);
        }

        // ---- V fragments, loaded ONCE for both tiles (above the fences) ----
        bhalf8 vf[4][2];
#pragma unroll
        for (int dt = 0; dt < 4; ++dt) {
            const short* vp = Vp + (size_t)(dt * 16 + c) * 2048 + kb + g * 8;
            vf[dt][0] = *(const bhalf8*)(vp);          // Vt is key-permuted
            vf[dt][1] = *(const bhalf8*)(vp + 32);     // to match packed P
        }

        float madd[4];
#pragma unroll
        for (int t = 0; t < 4; ++t) madd[t] = mp[kb + t * 16 + c] ? 0.f : -1e9f;

        // ================= tile A: softmax + exchange + PV =================
        {
            float p[4][4], tm[4];
#pragma unroll
            for (int r = 0; r < 4; ++r) {
                tm[r] = -1e30f;
#pragma unroll
                for (int t = 0; t < 4; ++t) {
                    p[t][r] = sA[t][r] * 0.125f + madd[t];
                    tm[r] = fmaxf(tm[r], p[t][r]);
                }
            }
#pragma unroll
            for (int r = 0; r < 4; ++r) {
                tm[r] = fmaxf(tm[r], __shfl_xor(tm[r], 1));
                tm[r] = fmaxf(tm[r], __shfl_xor(tm[r], 2));
                tm[r] = fmaxf(tm[r], __shfl_xor(tm[r], 4));
                tm[r] = fmaxf(tm[r], __shfl_xor(tm[r], 8));
            }
            float fac[4];
#pragma unroll
            for (int r = 0; r < 4; ++r) {
                const float nm = fmaxf(mA[r], tm[r]);
                fac[r] = __expf(mA[r] - nm);
                mA[r] = nm;
                float rs = 0.f;
#pragma unroll
                for (int t = 0; t < 4; ++t) {
                    p[t][r] = __expf(p[t][r] - nm);
                    rs += p[t][r];
                }
                rs += __shfl_xor(rs, 1);
                rs += __shfl_xor(rs, 2);
                rs += __shfl_xor(rs, 4);
                rs += __shfl_xor(rs, 8);
                lA[r] = lA[r] * fac[r] + rs;
            }
#pragma unroll
            for (int dt = 0; dt < 4; ++dt)
#pragma unroll
                for (int r = 0; r < 4; ++r) oA[dt][r] *= fac[r];

            asm volatile("" ::: "memory");
#pragma unroll
            for (int r = 0; r < 4; ++r) {
                uint2 w0;
                w0.x = cvt_pk_bf16(p[0][r], p[1][r]);
                w0.y = cvt_pk_bf16(p[2][r], p[3][r]);
                *(uint2*)&Plds[wid][g * 4 + r][c * 4] = w0;
            }
            asm volatile("s_waitcnt lgkmcnt(0)" ::: "memory");
            const bhalf8 pa0 = *(const bhalf8*)(&Plds[wid][c][g * 8]);
            const bhalf8 pa1 = *(const bhalf8*)(&Plds[wid][c][32 + g * 8]);
#pragma unroll
            for (int dt = 0; dt < 4; ++dt) {
                oA[dt] = MFMA(pa0, vf[dt][0], oA[dt]);
                oA[dt] = MFMA(pa1, vf[dt][1], oA[dt]);
            }
        }

        // ================= tile B: softmax + exchange + PV =================
        // (Plds reuse is safe: per-wave DS ops execute in order, so tile-A
        //  reads complete before tile-B writes to the same addresses.)
        {
            float p[4][4], tm[4];
#pragma unroll
            for (int r = 0; r < 4; ++r) {
                tm[r] = -1e30f;
#pragma unroll
                for (int t = 0; t < 4; ++t) {
                    p[t][r] = sB[t][r] * 0.125f + madd[t];
                    tm[r] = fmaxf(tm[r], p[t][r]);
                }
            }
#pragma unroll
            for (int r = 0; r < 4; ++r) {
                tm[r] = fmaxf(tm[r], __shfl_xor(tm[r], 1));
                tm[r] = fmaxf(tm[r], __shfl_xor(tm[r], 2));
                tm[r] = fmaxf(tm[r], __shfl_xor(tm[r], 4));
                tm[r] = fmaxf(tm[r], __shfl_xor(tm[r], 8));
            }
            float fac[4];
#pragma unroll
            for (int r = 0; r < 4; ++r) {
                const float nm = fmaxf(mB[r], tm[r]);
                fac[r] = __expf(mB[r] - nm);
                mB[r] = nm;
                float rs = 0.f;
#pragma unroll
                for (int t = 0; t < 4; ++t) {
                    p[t][r] = __expf(p[t][r] - nm);
                    rs += p[t][r];
                }
                rs += __shfl_xor(rs, 1);
                rs += __shfl_xor(rs, 2);
                rs += __shfl_xor(rs, 4);
                rs += __shfl_xor(rs, 8);
                lB[r] = lB[r] * fac[r] + rs;
            }
#pragma unroll
            for (int dt = 0; dt < 4; ++dt)
#pragma unroll
                for (int r = 0; r < 4; ++r) oB[dt][r] *= fac[r];

            asm volatile("" ::: "memory");
#pragma unroll
            for (int r = 0; r < 4; ++r) {
                uint2 w0;
                w0.x = cvt_pk_bf16(p[0][r], p[1][r]);
                w0.y = cvt_pk_bf16(p[2][r], p[3][r]);
                *(uint2*)&Plds[wid][g * 4 + r][c * 4] = w0;
            }
            asm volatile("s_waitcnt lgkmcnt(0)" ::: "memory");
            const bhalf8 pa0 = *(const bhalf8*)(&Plds[wid][c][g * 8]);
            const bhalf8 pa1 = *(const bhalf8*)(&Plds[wid][c][32 + g * 8]);
#pragma unroll
            for (int dt = 0; dt < 4; ++dt) {
                oB[dt] = MFMA(pa0, vf[dt][0], oB[dt]);
                oB[dt] = MFMA(pa1, vf[dt][1], oB[dt]);
            }
        }
    }

    // ---- publish per-wave partial state (rows 0..15 = A, 16..31 = B) ----
    if (c == 0) {
#pragma unroll
        for (int r = 0; r < 4; ++r) {
            mlds[wid][g * 4 + r]      = mA[r];
            llds[wid][g * 4 + r]      = lA[r];
            mlds[wid][16 + g * 4 + r] = mB[r];
            llds[wid][16 + g * 4 + r] = lB[r];
        }
    }
#pragma unroll
    for (int dt = 0; dt < 4; ++dt)
#pragma unroll
        for (int r = 0; r < 4; ++r) {
            olds[wid][g * 4 + r][dt * 16 + c]      = oA[dt][r];
            olds[wid][16 + g * 4 + r][dt * 16 + c] = oB[dt][r];
        }
    __syncthreads();

    // ---- cross-wave combine (2048 outputs, 4 per thread) ----
    float* op = out + (size_t)(b * 2048 + qbase) * 64;
#pragma unroll
    for (int i = 0; i < 4; ++i) {
        const int idx = tid + i * 512;        // 0..2047 over (row,d)
        const int row = idx >> 6, d = idx & 63;
        float M = mlds[0][row];
#pragma unroll
        for (int w = 1; w < 8; ++w) M = fmaxf(M, mlds[w][row]);
        float num = 0.f, den = 0.f;
#pragma unroll
        for (int w = 0; w < 8; ++w) {
            const float wt = __expf(mlds[w][row] - M);
            num += wt * olds[w][row][d];
            den += wt * llds[w][row];
        }
        op[row * 64 + d] = num / den;
    }
}

extern "C" void kernel_launch(void* const* d_in, const int* in_sizes, int n_in,
                              void* d_out, int out_size, void* d_ws, size_t ws_size,
                              hipStream_t stream) {
    const float* x    = (const float*)d_in[0];
    const int*   mask = (const int*)d_in[1];
    const float* Wq   = (const float*)d_in[2];
    const float* bq   = (const float*)d_in[3];
    const float* Wk   = (const float*)d_in[4];
    const float* bk   = (const float*)d_in[5];
    const float* Wv   = (const float*)d_in[6];
    const float* bv   = (const float*)d_in[7];
    float* out = (float*)d_out;

    short* Qb = (short*)d_ws;                 // 4*2048*64
    short* Kb = Qb + 4 * 2048 * 64;           // 4*2048*64
    short* Vt = Kb + 4 * 2048 * 64;           // 4*2048*64 ([B][64][2048], key-permuted)

    proj_kernel<<<512, 256, 0, stream>>>(x, Wq, bq, Wk, bk, Wv, bv, Qb, Kb, Vt);
    attn_kernel<<<256, 512, 0, stream>>>(Qb, Kb, Vt, mask, out);
}